// Round 10
// baseline (805.408 us; speedup 1.0000x reference)
//
#include <hip/hip_runtime.h>
#include <hip/hip_bf16.h>

#define N_NODES 50000
#define N_EDGES 800000
#define ESM_DIM 1280
#define HID_DIM 256
#define N_HEADS 8
#define HD_DIM 32
#define N_LAYERS 3
#define B_SZ 4096
#define M_SZ 8
#define AA_SZ 21

typedef __bf16 bf16x8 __attribute__((ext_vector_type(8)));
typedef float f32x4 __attribute__((ext_vector_type(4)));
typedef unsigned short ushort8 __attribute__((ext_vector_type(8)));
typedef unsigned int uint;
typedef uint uint4v __attribute__((ext_vector_type(4)));

__device__ __forceinline__ float lreluf(float x) { return x > 0.f ? x : 0.2f * x; }
__device__ __forceinline__ float eluf(float x)   { return x > 0.f ? x : expm1f(x); }
__device__ __forceinline__ float b2f(unsigned short u) { return __uint_as_float(((uint)u) << 16); }

__device__ __forceinline__ unsigned short bf16_rne(float f) {
    uint u = __float_as_uint(f);
    uint r = u + 0x7FFFu + ((u >> 16) & 1u);
    return (unsigned short)(r >> 16);
}

__device__ __forceinline__ float waveReduceSum(float v) {
#pragma unroll
    for (int off = 32; off > 0; off >>= 1) v += __shfl_xor(v, off, 64);
    return v;
}

// ---------------- weight transpose: W[K][N] f32 -> BT[N][K] bf16 ----------
__global__ void wsplit_t(const float* __restrict__ W, unsigned short* __restrict__ BTh,
                         int K, int N) {
    int idx = blockIdx.x * 256 + threadIdx.x;
    if (idx >= K * N) return;
    int k = idx / N, n = idx - k * N;
    BTh[(size_t)n * K + k] = bf16_rne(W[idx]);
}

// ---------------- MFMA GEMM v7: C[M,256] = A[M,K] @ BT[256,K]^T
// 128x128 tile, BK=32, 4 waves, 16 MFMA/iter/wave. LDS 32KB:
// A bf16 [2][8KB] + B bf16 [2][8KB]. AF32: A reg-staged (T14 split:
// load->regs early, cvt_pk + ds_write after compute). lin: A gload_lds.
// Counted vmcnt (never 0 mid-loop). Bijective XCD-chunked block swizzle.
template<int AF32, int OUTMODE>
__global__ __launch_bounds__(256) void gemm_v7(
    const char* __restrict__ Ap, const unsigned short* __restrict__ BT,
    const float* __restrict__ bias, float* __restrict__ C,
    unsigned short* __restrict__ Cb, int M, int K, int nwg) {
    __shared__ __align__(16) char smem[4 * 8192];

    const int tid = threadIdx.x;
    // bijective XCD-chunked swizzle (m204): pairs sharing A-panel -> same XCD
    const int dd = blockIdx.x;
    const int q = nwg >> 3, r = nwg & 7;
    const int xcd = dd & 7;
    const int wg = (xcd < r ? xcd * (q + 1) : r * (q + 1) + (xcd - r) * q) + (dd >> 3);
    const int bn = (wg & 1) << 7;
    const int bm = (wg >> 1) << 7;

    const int wv = tid >> 6, lane = tid & 63;
    const int wr = wv >> 1, wc = wv & 1;
    const int lr = lane & 15, lk = lane >> 4;

    // ---- B staging (gload_lds): 8 chunks of 1KB; wave handles {wv, wv+4}
    size_t bSrc[2]; int bDst[2];
#pragma unroll
    for (int i = 0; i < 2; ++i) {
        int c = wv + i * 4;
        int rb = c * 16 + (lane >> 2);
        int g = (lane & 3) ^ ((rb >> 1) & 3);
        bSrc[i] = (size_t)(bn + rb) * K * 2 + (size_t)g * 16;
        bDst[i] = c * 1024;
    }
    auto issueB = [&](int buf, int k0) {
        char* dstbase = smem + 16384 + buf * 8192;
        const size_t kb = (size_t)k0 * 2;
#pragma unroll
        for (int i = 0; i < 2; ++i)
            __builtin_amdgcn_global_load_lds(
                (const __attribute__((address_space(1))) void*)((const char*)BT + bSrc[i] + kb),
                (__attribute__((address_space(3))) void*)(dstbase + bDst[i]), 16, 0, 0);
    };

    // ---- A staging
    const float* aRowP = nullptr;  // AF32 reg-staged
    int aw0 = 0, aw1 = 0;
    size_t aSrc[2]; int aDst[2];   // lin gload_lds
    if constexpr (AF32) {
        const int sr = tid >> 1, sh = tid & 1;
        int srg = bm + sr; if (srg >= M) srg = M - 1;
        aRowP = (const float*)Ap + (size_t)srg * K + sh * 16;
        const uint aswz = (uint)((sr >> 1) & 3);
        aw0 = sr * 64 + (int)((((uint)(2 * sh)) ^ aswz) * 16);
        aw1 = sr * 64 + (int)((((uint)(2 * sh + 1)) ^ aswz) * 16);
    } else {
#pragma unroll
        for (int i = 0; i < 2; ++i) {
            int c = wv + i * 4;
            int rl = c * 16 + (lane >> 2);
            int rg = bm + rl; if (rg >= M) rg = M - 1;
            int g = (lane & 3) ^ ((rl >> 1) & 3);
            aSrc[i] = (size_t)rg * K * 2 + (size_t)g * 16;
            aDst[i] = c * 1024;
        }
    }
    auto issueA_lds = [&](int buf, int k0) {
        char* dstbase = smem + buf * 8192;
        const size_t ka = (size_t)k0 * 2;
#pragma unroll
        for (int i = 0; i < 2; ++i)
            __builtin_amdgcn_global_load_lds(
                (const __attribute__((address_space(1))) void*)(Ap + aSrc[i] + ka),
                (__attribute__((address_space(3))) void*)(dstbase + aDst[i]), 16, 0, 0);
    };
    auto cvtWriteA = [&](int buf, float4 a0, float4 a1, float4 a2, float4 a3) {
        char* dst = smem + buf * 8192;
        uint h0, h1, h2, h3, h4, h5, h6, h7;
        asm("v_cvt_pk_bf16_f32 %0, %1, %2" : "=v"(h0) : "v"(a0.x), "v"(a0.y));
        asm("v_cvt_pk_bf16_f32 %0, %1, %2" : "=v"(h1) : "v"(a0.z), "v"(a0.w));
        asm("v_cvt_pk_bf16_f32 %0, %1, %2" : "=v"(h2) : "v"(a1.x), "v"(a1.y));
        asm("v_cvt_pk_bf16_f32 %0, %1, %2" : "=v"(h3) : "v"(a1.z), "v"(a1.w));
        asm("v_cvt_pk_bf16_f32 %0, %1, %2" : "=v"(h4) : "v"(a2.x), "v"(a2.y));
        asm("v_cvt_pk_bf16_f32 %0, %1, %2" : "=v"(h5) : "v"(a2.z), "v"(a2.w));
        asm("v_cvt_pk_bf16_f32 %0, %1, %2" : "=v"(h6) : "v"(a3.x), "v"(a3.y));
        asm("v_cvt_pk_bf16_f32 %0, %1, %2" : "=v"(h7) : "v"(a3.z), "v"(a3.w));
        uint4v v0 = {h0, h1, h2, h3}, v1 = {h4, h5, h6, h7};
        *(uint4v*)(dst + aw0) = v0;
        *(uint4v*)(dst + aw1) = v1;
    };

    f32x4 acc[4][4] = {};
    const int NT = K / 32;
    float4 ar0, ar1, ar2, ar3;

    // prologue: stage tile 0
    if constexpr (AF32) {
        const float4* ap = (const float4*)aRowP;
        ar0 = ap[0]; ar1 = ap[1]; ar2 = ap[2]; ar3 = ap[3];
        issueB(0, 0);
        cvtWriteA(0, ar0, ar1, ar2, ar3);        // compiler waits A regs only
        asm volatile("s_waitcnt lgkmcnt(0)" ::: "memory");
    } else {
        issueA_lds(0, 0);
        issueB(0, 0);
    }

    for (int t = 0; t < NT; ++t) {
        const int cur = t & 1;
        if (t + 1 < NT) {
            const int k0 = (t + 1) * 32;
            if constexpr (AF32) {
                const float4* ap = (const float4*)(aRowP + k0);
                ar0 = ap[0]; ar1 = ap[1]; ar2 = ap[2]; ar3 = ap[3];  // A(t+1)->regs
                issueB(cur ^ 1, k0);                                 // B(t+1) in flight
                asm volatile("s_waitcnt vmcnt(6)" ::: "memory");     // B(t) landed
            } else {
                issueA_lds(cur ^ 1, k0);
                issueB(cur ^ 1, k0);
                asm volatile("s_waitcnt vmcnt(4)" ::: "memory");
            }
        } else {
            asm volatile("s_waitcnt vmcnt(0)" ::: "memory");
        }
        __builtin_amdgcn_s_barrier();            // tile t resident for all waves
        __builtin_amdgcn_sched_barrier(0);

        const unsigned short* Abl = (const unsigned short*)(smem + cur * 8192);
        const unsigned short* Bbl = (const unsigned short*)(smem + 16384 + cur * 8192);
        bf16x8 ah[4];
#pragma unroll
        for (int m = 0; m < 4; ++m) {
            int ra = wr * 64 + m * 16 + lr;
            ah[m] = __builtin_bit_cast(bf16x8,
                *(const ushort8*)&Abl[ra * 32 + ((lk ^ ((ra >> 1) & 3)) * 8)]);
        }
#pragma unroll
        for (int n = 0; n < 4; ++n) {
            int rb = wc * 64 + n * 16 + lr;
            bf16x8 bh = __builtin_bit_cast(bf16x8,
                *(const ushort8*)&Bbl[rb * 32 + ((lk ^ ((rb >> 1) & 3)) * 8)]);
#pragma unroll
            for (int m = 0; m < 4; ++m)
                acc[m][n] = __builtin_amdgcn_mfma_f32_16x16x32_bf16(ah[m], bh, acc[m][n], 0, 0, 0);
        }
        __builtin_amdgcn_sched_barrier(0);
        if (t + 1 < NT) {
            if constexpr (AF32) {
                cvtWriteA(cur ^ 1, ar0, ar1, ar2, ar3);  // A(t+1) -> LDS
                asm volatile("s_waitcnt lgkmcnt(0)" ::: "memory");
            }
            __builtin_amdgcn_s_barrier();        // reads done + A(t+1) visible
        }
    }

    // epilogue: col = lane&15, row = (lane>>4)*4 + r
#pragma unroll
    for (int n = 0; n < 4; ++n) {
        int col = bn + wc * 64 + n * 16 + lr;
        float bi = (OUTMODE == 0 && bias) ? bias[col] : 0.f;
#pragma unroll
        for (int m = 0; m < 4; ++m) {
#pragma unroll
            for (int rr = 0; rr < 4; ++rr) {
                int rowg = bm + wr * 64 + m * 16 + lk * 4 + rr;
                if (rowg < M) {
                    float v = acc[m][n][rr] + bi;
                    if constexpr (OUTMODE == 0) {
                        C[(size_t)rowg * HID_DIM + col] = v;
                        Cb[(size_t)rowg * HID_DIM + col] = bf16_rne(v);
                    } else {
                        Cb[(size_t)rowg * HID_DIM + col] = bf16_rne(v);
                    }
                }
            }
        }
    }
}

// ---------------- attention dot products per (node, head), bf16 xs ----------
__global__ void att_dots(const unsigned short* __restrict__ xs_b,
                         const float* __restrict__ a_src, const float* __restrict__ a_dst,
                         float* __restrict__ al_s, float* __restrict__ al_d) {
    int idx = blockIdx.x * 256 + threadIdx.x;
    if (idx >= N_NODES * N_HEADS) return;
    int h = idx & 7;
    const ushort8* v = (const ushort8*)(xs_b + (size_t)idx * HD_DIM);
    const float4* as = (const float4*)(a_src + h * HD_DIM);
    const float4* ad = (const float4*)(a_dst + h * HD_DIM);
    float s1 = 0.f, s2 = 0.f;
#pragma unroll
    for (int q = 0; q < 4; ++q) {
        ushort8 xv = v[q];
        float4 a1 = as[2 * q], a1b = as[2 * q + 1];
        float4 a2 = ad[2 * q], a2b = ad[2 * q + 1];
        float x0 = b2f(xv[0]), x1 = b2f(xv[1]), x2 = b2f(xv[2]), x3 = b2f(xv[3]);
        float x4 = b2f(xv[4]), x5 = b2f(xv[5]), x6 = b2f(xv[6]), x7 = b2f(xv[7]);
        s1 += x0 * a1.x + x1 * a1.y + x2 * a1.z + x3 * a1.w
            + x4 * a1b.x + x5 * a1b.y + x6 * a1b.z + x7 * a1b.w;
        s2 += x0 * a2.x + x1 * a2.y + x2 * a2.z + x3 * a2.w
            + x4 * a2b.x + x5 * a2b.y + x6 * a2b.z + x7 * a2b.w;
    }
    al_s[idx] = s1;
    al_d[idx] = s2;
}

// ---------------- CSR build ----------------
__global__ void hist_kernel(const int* __restrict__ dst, int* __restrict__ counts) {
    int e = blockIdx.x * 256 + threadIdx.x;
    if (e < N_EDGES) atomicAdd(&counts[dst[e]], 1);
}

__global__ __launch_bounds__(1024) void scan_kernel(const int* __restrict__ counts,
                                                    int* __restrict__ offsets,
                                                    int* __restrict__ cursor) {
    __shared__ int sums[1024];
    const int t = threadIdx.x;
    const int CH = (N_NODES + 1023) / 1024;
    const int base = t * CH;
    int local = 0;
    for (int i = 0; i < CH; ++i) {
        int idx = base + i;
        if (idx < N_NODES) local += counts[idx];
    }
    sums[t] = local;
    __syncthreads();
    for (int off = 1; off < 1024; off <<= 1) {
        int v = (t >= off) ? sums[t - off] : 0;
        __syncthreads();
        sums[t] += v;
        __syncthreads();
    }
    int run = (t == 0) ? 0 : sums[t - 1];
    for (int i = 0; i < CH; ++i) {
        int idx = base + i;
        if (idx < N_NODES) {
            offsets[idx] = run;
            cursor[idx] = run;
            run += counts[idx];
        }
    }
}

__global__ void scatter_kernel(const int* __restrict__ src, const int* __restrict__ dst,
                               int* __restrict__ cursor, int* __restrict__ csr_src) {
    int e = blockIdx.x * 256 + threadIdx.x;
    if (e < N_EDGES) {
        int d = dst[e];
        int p = atomicAdd(&cursor[d], 1);
        csr_src[p] = src[e];
    }
}

// ---------------- fused GAT aggregation (two-phase) + ELU + residual + LN ----
__global__ __launch_bounds__(256) void gat_aggregate(
    const unsigned short* __restrict__ xs_b, const float* __restrict__ al_s,
    const float* __restrict__ al_d,
    const int* __restrict__ offsets, const int* __restrict__ counts,
    const int* __restrict__ csr_src,
    const float* __restrict__ bias, const float* __restrict__ ln_g,
    const float* __restrict__ ln_b,
    const float* __restrict__ h_in, float* __restrict__ h_out,
    unsigned short* __restrict__ hb_out) {
    const int wave = threadIdx.x >> 6;
    const int lane = threadIdx.x & 63;
    const int n = blockIdx.x * 4 + wave;
    if (n >= N_NODES) return;
    const int hh = lane >> 3;
    const float aldn = al_d[n * N_HEADS + hh];
    const float e0 = lreluf(al_s[n * N_HEADS + hh] + aldn);
    const int start = offsets[n];
    const int cnt = counts[n];
    const int* sp = csr_src + start;

    // phase 1: max, 8 edge-slots in parallel per head (lane = hh*8 + es)
    const int es = lane & 7;
    float m = e0;
    for (int j = es; j < cnt; j += 8) {
        int s1 = sp[j];
        m = fmaxf(m, lreluf(al_s[s1 * N_HEADS + hh] + aldn));
    }
    m = fmaxf(m, __shfl_xor(m, 1, 64));
    m = fmaxf(m, __shfl_xor(m, 2, 64));
    m = fmaxf(m, __shfl_xor(m, 4, 64));

    // phase 2: no-rescale accumulation (independent chains, deep unroll)
    const ushort4* xv4 = (const ushort4*)xs_b;
    float p0 = __expf(e0 - m);
    float s = p0;
    ushort4 x0 = xv4[(size_t)n * 64 + lane];
    float ax = p0 * b2f(x0.x), ay = p0 * b2f(x0.y);
    float az = p0 * b2f(x0.z), aw = p0 * b2f(x0.w);
#pragma unroll 8
    for (int j = 0; j < cnt; ++j) {
        int s1 = sp[j];
        float e = lreluf(al_s[s1 * N_HEADS + hh] + aldn);
        float pj = __expf(e - m);
        ushort4 xr = xv4[(size_t)s1 * 64 + lane];
        s += pj;
        ax += pj * b2f(xr.x);
        ay += pj * b2f(xr.y);
        az += pj * b2f(xr.z);
        aw += pj * b2f(xr.w);
    }
    const float inv = 1.f / s;
    float4 bv = ((const float4*)bias)[lane];
    float4 hp = ((const float4*)h_in)[(size_t)n * 64 + lane];
    float v0 = eluf(ax * inv + bv.x) + hp.x;
    float v1 = eluf(ay * inv + bv.y) + hp.y;
    float v2 = eluf(az * inv + bv.z) + hp.z;
    float v3 = eluf(aw * inv + bv.w) + hp.w;

    float mu = waveReduceSum(v0 + v1 + v2 + v3) * (1.f / 256.f);
    float d0 = v0 - mu, d1 = v1 - mu, d2 = v2 - mu, d3 = v3 - mu;
    float var = waveReduceSum(d0 * d0 + d1 * d1 + d2 * d2 + d3 * d3) * (1.f / 256.f);
    float rstd = rsqrtf(var + 1e-5f);
    float4 g = ((const float4*)ln_g)[lane];
    float4 b2v = ((const float4*)ln_b)[lane];
    float4 outv;
    outv.x = d0 * rstd * g.x + b2v.x;
    outv.y = d1 * rstd * g.y + b2v.y;
    outv.z = d2 * rstd * g.z + b2v.z;
    outv.w = d3 * rstd * g.w + b2v.w;
    ((float4*)h_out)[(size_t)n * 64 + lane] = outv;
    ushort4 ob;
    ob.x = bf16_rne(outv.x); ob.y = bf16_rne(outv.y);
    ob.z = bf16_rne(outv.z); ob.w = bf16_rne(outv.w);
    ((ushort4*)hb_out)[(size_t)n * 64 + lane] = ob;
}

// ---------------- predict: one wave per batch element ----------------
__global__ __launch_bounds__(256) void predict_kernel(
    const float* __restrict__ h, const int* __restrict__ sites,
    const float* __restrict__ muts,
    const float* __restrict__ pq_w, const float* __restrict__ pq_b,
    const float* __restrict__ w1, const float* __restrict__ b1,
    const float* __restrict__ w2, const float* __restrict__ b2,
    float* __restrict__ out) {
    const int wave = threadIdx.x >> 6;
    const int lane = threadIdx.x & 63;
    const int b = blockIdx.x * 4 + wave;
    __shared__ __align__(16) float pooled_s[4][288];

    float scores[M_SZ];
    float4 pv = ((const float4*)pq_w)[lane];
#pragma unroll
    for (int mi = 0; mi < M_SZ; ++mi) {
        int site = sites[b * M_SZ + mi];
        float4 hv = ((const float4*)h)[(size_t)site * 64 + lane];
        float part = hv.x * pv.x + hv.y * pv.y + hv.z * pv.z + hv.w * pv.w;
        if (lane < AA_SZ) part += muts[(size_t)(b * M_SZ + mi) * AA_SZ + lane] * pq_w[256 + lane];
        part = waveReduceSum(part);
        scores[mi] = part + pq_b[0];
    }
    float mx = scores[0];
#pragma unroll
    for (int mi = 1; mi < M_SZ; ++mi) mx = fmaxf(mx, scores[mi]);
    float se = 0.f;
#pragma unroll
    for (int mi = 0; mi < M_SZ; ++mi) { scores[mi] = __expf(scores[mi] - mx); se += scores[mi]; }
    const float inv = 1.f / se;

    float4 pooled = make_float4(0.f, 0.f, 0.f, 0.f);
    float pooledMut = 0.f;
#pragma unroll
    for (int mi = 0; mi < M_SZ; ++mi) {
        int site = sites[b * M_SZ + mi];
        float w = scores[mi] * inv;
        float4 hv = ((const float4*)h)[(size_t)site * 64 + lane];
        pooled.x += w * hv.x; pooled.y += w * hv.y; pooled.z += w * hv.z; pooled.w += w * hv.w;
        if (lane < AA_SZ) pooledMut += w * muts[(size_t)(b * M_SZ + mi) * AA_SZ + lane];
    }
    ((float4*)&pooled_s[wave][0])[lane] = pooled;
    if (lane < AA_SZ) pooled_s[wave][256 + lane] = pooledMut;
    __syncthreads();

    float hid0 = b1[lane], hid1 = b1[lane + 64];
    for (int k = 0; k < HID_DIM + AA_SZ; ++k) {
        float pk = pooled_s[wave][k];
        hid0 += pk * w1[k * 128 + lane];
        hid1 += pk * w1[k * 128 + lane + 64];
    }
    hid0 = fmaxf(hid0, 0.f);
    hid1 = fmaxf(hid1, 0.f);
    float r = hid0 * w2[lane] + hid1 * w2[lane + 64];
    r = waveReduceSum(r);
    if (lane == 0) out[b] = r + b2[0];
}

// ---------------- host ----------------
extern "C" void kernel_launch(void* const* d_in, const int* in_sizes, int n_in,
                              void* d_out, int out_size, void* d_ws, size_t ws_size,
                              hipStream_t stream) {
    const float* x        = (const float*)d_in[0];
    const int*   eidx     = (const int*)d_in[1];
    const int*   sites    = (const int*)d_in[2];
    const float* muts     = (const float*)d_in[3];
    const float* proj_w   = (const float*)d_in[5];
    const float* proj_b   = (const float*)d_in[6];
    const float* lin_w    = (const float*)d_in[7];
    const float* att_src  = (const float*)d_in[8];
    const float* att_dst  = (const float*)d_in[9];
    const float* gat_b    = (const float*)d_in[10];
    const float* ln_g     = (const float*)d_in[11];
    const float* ln_b     = (const float*)d_in[12];
    const float* pq_w     = (const float*)d_in[13];
    const float* pq_b     = (const float*)d_in[14];
    const float* vh_w1    = (const float*)d_in[15];
    const float* vh_b1    = (const float*)d_in[16];
    const float* vh_w2    = (const float*)d_in[17];
    const float* vh_b2    = (const float*)d_in[18];

    char* ws = (char*)d_ws;
    const size_t SZ_H = (size_t)N_NODES * HID_DIM * sizeof(float);  // 51.2 MB
    float* h1   = (float*)ws;                 ws += SZ_H;
    float* h2   = (float*)ws;                 ws += SZ_H;
    unsigned short* hb   = (unsigned short*)ws; ws += (size_t)N_NODES * HID_DIM * 2;
    unsigned short* xs_b = (unsigned short*)ws; ws += (size_t)N_NODES * HID_DIM * 2;
    float* al_s = (float*)ws;                 ws += (size_t)N_NODES * N_HEADS * 4;
    float* al_d = (float*)ws;                 ws += (size_t)N_NODES * N_HEADS * 4;
    int* counts  = (int*)ws;                  ws += 200192;
    int* offsets = (int*)ws;                  ws += 200192;
    int* cursor  = (int*)ws;                  ws += 200192;
    int* csr_src = (int*)ws;                  ws += (size_t)N_EDGES * 4;
    unsigned short* pBTh = (unsigned short*)ws; ws += (size_t)ESM_DIM * HID_DIM * 2;
    unsigned short* lBTh = (unsigned short*)ws; ws += (size_t)N_LAYERS * HID_DIM * HID_DIM * 2;

    const int* e_src = eidx;
    const int* e_dst = eidx + N_EDGES;

    // CSR build
    hipMemsetAsync(counts, 0, N_NODES * sizeof(int), stream);
    hist_kernel<<<(N_EDGES + 255) / 256, 256, 0, stream>>>(e_dst, counts);
    scan_kernel<<<1, 1024, 0, stream>>>(counts, offsets, cursor);
    scatter_kernel<<<(N_EDGES + 255) / 256, 256, 0, stream>>>(e_src, e_dst, cursor, csr_src);

    // weight transpose (bf16)
    wsplit_t<<<(ESM_DIM * HID_DIM + 255) / 256, 256, 0, stream>>>(proj_w, pBTh, ESM_DIM, HID_DIM);
    for (int l = 0; l < N_LAYERS; ++l) {
        wsplit_t<<<(HID_DIM * HID_DIM + 255) / 256, 256, 0, stream>>>(
            lin_w + (size_t)l * HID_DIM * HID_DIM,
            lBTh + (size_t)l * HID_DIM * HID_DIM, HID_DIM, HID_DIM);
    }

    const int nwg = 2 * ((N_NODES + 127) / 128);   // 782
    // proj: fp32 h1 + bias + bf16 copy hb
    gemm_v7<1, 0><<<nwg, 256, 0, stream>>>((const char*)x, pBTh, proj_b, h1, hb,
                                           N_NODES, ESM_DIM, nwg);

    float* hin = h1;
    float* hout = h2;
    for (int l = 0; l < N_LAYERS; ++l) {
        // lin: A = bf16 copy of h; bf16 xs out
        gemm_v7<0, 1><<<nwg, 256, 0, stream>>>(
            (const char*)hb, lBTh + (size_t)l * HID_DIM * HID_DIM,
            nullptr, nullptr, xs_b, N_NODES, HID_DIM, nwg);
        att_dots<<<(N_NODES * N_HEADS + 255) / 256, 256, 0, stream>>>(
            xs_b, att_src + l * N_HEADS * HD_DIM, att_dst + l * N_HEADS * HD_DIM, al_s, al_d);
        gat_aggregate<<<(N_NODES + 3) / 4, 256, 0, stream>>>(
            xs_b, al_s, al_d, offsets, counts, csr_src,
            gat_b + l * HID_DIM, ln_g + l * HID_DIM, ln_b + l * HID_DIM,
            hin, hout, hb);
        float* t = hin; hin = hout; hout = t;
    }

    predict_kernel<<<B_SZ / 4, 256, 0, stream>>>(
        hin, sites, muts, pq_w, pq_b, vh_w1, vh_b1, vh_w2, vh_b2, (float*)d_out);
}